// Round 3
// baseline (208.949 us; speedup 1.0000x reference)
//
#include <hip/hip_runtime.h>

// YOLOv1 loss, faithful to the reference (including the in-place corner bug).
// R9: duty-cycle restructure vs R8.
//   Diagnosis: R6/R7/R8 (three different access structures) all land at
//   73-78 us, ~2.6 TB/s delivered line-traffic, HBM 16%, VALU 7%. Common
//   property: every block drains vmcnt(0) then computes with ZERO loads in
//   flight -> memory-issue duty cycle ~40%. 192.7 MB at 6.3 TB/s needs 31 us;
//   74 ~= 31 / 0.42. Fix = streaming analog of the GEMM T3/T4 rule: never
//   drain vmcnt in the main loop.
//   Structure: single-wave blocks (wave owns its LDS slab -> NO barriers),
//   double-buffered global_load_lds staging, counted s_waitcnt vmcnt(15):
//   while computing tile t, tile t+1's 15 loads (15360 B) stay in flight.
//   5 blocks/CU x 15 KB ~= 75 KB outstanding per CU >> ~8 KB BDP.
//   WAR on buffer reuse: lgkmcnt(0)+sched_barrier after compute guarantees
//   all ds_reads landed before the next stage overwrites that buffer.

constexpr int   BLK   = 64;             // 1 wave per block
constexpr int   TILE  = 64;             // cells per tile
constexpr int   NC    = 16384 * 7 * 7;  // 802816 cells
constexpr int   NTILE = NC / TILE;      // 12544 tiles
constexpr int   GRID  = 3136;           // 4 tiles per block, exact
constexpr int   ITERS = NTILE / GRID;   // 4
constexpr float CELL  = 1.0f / 7.0f;
constexpr float LC    = 5.0f;
constexpr float LN    = 0.5f;

__device__ inline void gload_lds16(const float4* g, float4* l)
{
    __builtin_amdgcn_global_load_lds(
        (const __attribute__((address_space(1))) void*)g,
        (__attribute__((address_space(3))) void*)l,
        16, 0, 0);
}

// Stage one 64-cell tile (T slab 480 float4 | P slab 480 float4) into LDS.
// 15 wave-instructions, lane-contiguous dest as global_load_lds requires.
// Instruction k=7 straddles the T/P switch: source address is per-lane (ok).
__device__ inline void stage_tile(const float* __restrict__ P,
                                  const float* __restrict__ T,
                                  int t, float4* dst, int lane)
{
    const float4* gT = reinterpret_cast<const float4*>(T + (size_t)t * 1920);
    const float4* gP = reinterpret_cast<const float4*>(P + (size_t)t * 1920);
    #pragma unroll
    for (int k = 0; k < 15; ++k) {
        const int idx = k * 64 + lane;                  // 0..959
        gload_lds16(idx < 480 ? gT + idx : gP + (idx - 480), dst + idx);
    }
}

__launch_bounds__(BLK, 4)               // VGPR cap 128; LDS caps blocks at 5/CU
__global__ void yolo_partial(const float* __restrict__ P, const float* __restrict__ T,
                             float4* __restrict__ ws)
{
    __shared__ float4 s4[1920];         // 2 x 960 float4 = 30720 B (double buffer)
    const int lane = threadIdx.x;

    float a_cls = 0.f, a_conf = 0.f, a_cw = 0.f, a_noobj = 0.f;

    // prologue: stage first tile into buffer 0
    stage_tile(P, T, blockIdx.x, s4, lane);

    #pragma unroll
    for (int it = 0; it < ITERS; ++it) {
        const int cur = it & 1;

        // issue next tile's loads BEFORE waiting on the current tile
        if (it + 1 < ITERS)
            stage_tile(P, T, blockIdx.x + (it + 1) * GRID, s4 + ((it + 1) & 1) * 960, lane);

        // counted wait: current tile's 15 loads landed; next tile's stay in flight
        if (it + 1 < ITERS) asm volatile("s_waitcnt vmcnt(15)" ::: "memory");
        else                asm volatile("s_waitcnt vmcnt(0)"  ::: "memory");
        __builtin_amdgcn_sched_barrier(0);

        // ---- this lane's cell from LDS: 30 ds_read_b64 ----
        const float* sf  = reinterpret_cast<const float*>(s4 + cur * 960);
        const float* myT = sf + (size_t)lane * 30;
        const float* myP = sf + 1920 + (size_t)lane * 30;
        float tv[30], pv[30];
        #pragma unroll
        for (int j = 0; j < 15; ++j) {
            float2 a = reinterpret_cast<const float2*>(myT)[j];
            tv[2 * j] = a.x; tv[2 * j + 1] = a.y;
            float2 b = reinterpret_cast<const float2*>(myP)[j];
            pv[2 * j] = b.x; pv[2 * j + 1] = b.y;
        }

        // argmax over t[10:30] with p-payload, first occurrence (strict >)
        float best = tv[10], pk = pv[10];
        #pragma unroll
        for (int k = 11; k < 30; ++k) {
            if (tv[k] > best) { best = tv[k]; pk = pv[k]; }
        }

        const float t4    = tv[4];
        const float obj   = (t4 == 1.0f) ? 1.0f : 0.0f;
        const float noobj = (t4 == 0.0f) ? 1.0f : 0.0f;

        float d4 = pv[4] - t4;
        float d9 = pv[9] - tv[9];
        a_noobj += noobj * (d4 * d4 + d9 * d9);

        // target corners (faithful bug: x2 uses already-updated x1)
        float tw2 = tv[2] * tv[2], th2 = tv[3] * tv[3];
        float tx1 = tv[0] * CELL - 0.5f * tw2;
        float tx2 = tx1 * CELL + 0.5f * tw2;
        float ty1 = tv[1] * CELL - 0.5f * th2;
        float ty2 = ty1 * CELL + 0.5f * th2;
        float area_t = (tx2 - tx1) * (ty2 - ty1);

        float iou0, iou1;
        #pragma unroll
        for (int b = 0; b < 2; ++b) {
            float bw2 = pv[5 * b + 2] * pv[5 * b + 2];
            float bh2 = pv[5 * b + 3] * pv[5 * b + 3];
            float px1 = pv[5 * b + 0] * CELL - 0.5f * bw2;
            float px2 = px1 * CELL + 0.5f * bw2;
            float py1 = pv[5 * b + 1] * CELL - 0.5f * bh2;
            float py2 = py1 * CELL + 0.5f * bh2;
            float ltx = fmaxf(px1, tx1), lty = fmaxf(py1, ty1);
            float rbx = fminf(px2, tx2), rby = fminf(py2, ty2);
            float inter = fmaxf(rbx - ltx, 0.0f) * fmaxf(rby - lty, 0.0f);
            float area_p = (px2 - px1) * (py2 - py1);
            float iou = inter / (area_p + area_t - inter);
            if (b == 0) iou0 = iou; else iou1 = iou;
        }
        const bool b1 = (iou1 > iou0);   // jnp.argmax: first on ties

        float cpx = b1 ? pv[5] : pv[0], ctx = b1 ? tv[5] : tv[0];
        float cpy = b1 ? pv[6] : pv[1], cty = b1 ? tv[6] : tv[1];
        float cpw = b1 ? pv[7] : pv[2], ctw = b1 ? tv[7] : tv[2];
        float cph = b1 ? pv[8] : pv[3], cth = b1 ? tv[8] : tv[3];
        float cpc = b1 ? pv[9] : pv[4], ctc = b1 ? tv[9] : tv[4];

        float dx = cpx - ctx, dy = cpy - cty;
        float dw = cpw - ctw, dh = cph - cth;
        a_cw   += obj * (dx * dx + dy * dy + dw * dw + dh * dh);
        float dc = cpc - ctc;
        a_conf += obj * dc * dc;
        float dk = pk - best;
        a_cls  += obj * dk * dk;

        // WAR fence: all ds_reads of this buffer landed before the stage in
        // the NEXT iteration overwrites it. lgkmcnt(0) is nearly free here
        // (compute already consumed the reads).
        asm volatile("s_waitcnt lgkmcnt(0)" ::: "memory");
        __builtin_amdgcn_sched_barrier(0);
    }

    // ---- single-wave reduction, one float4 store per block ----
    float vals[4] = { a_cls, a_conf, a_cw, a_noobj };
    #pragma unroll
    for (int c = 0; c < 4; ++c) {
        #pragma unroll
        for (int off = 32; off > 0; off >>= 1)
            vals[c] += __shfl_down(vals[c], off, 64);
    }
    if (lane == 0)
        ws[blockIdx.x] = make_float4(vals[0], vals[1], vals[2], vals[3]);
}

__launch_bounds__(1024, 1)
__global__ void yolo_reduce(const float4* __restrict__ ws, float* __restrict__ out)
{
    __shared__ float red[4][16];
    const int tid = threadIdx.x;

    float s0 = 0.f, s1 = 0.f, s2 = 0.f, s3 = 0.f;
    for (int b = tid; b < GRID; b += 1024) {    // coalesced float4 stream
        float4 v = ws[b];
        s0 += v.x; s1 += v.y; s2 += v.z; s3 += v.w;
    }
    float vals[4] = { s0, s1, s2, s3 };
    #pragma unroll
    for (int c = 0; c < 4; ++c) {
        #pragma unroll
        for (int off = 32; off > 0; off >>= 1)
            vals[c] += __shfl_down(vals[c], off, 64);
        if ((tid & 63) == 0) red[c][tid >> 6] = vals[c];
    }
    __syncthreads();
    if (tid == 0) {
        float t0 = 0.f, t1 = 0.f, t2 = 0.f, t3 = 0.f;
        #pragma unroll
        for (int w = 0; w < 16; ++w) {
            t0 += red[0][w]; t1 += red[1][w]; t2 += red[2][w]; t3 += red[3][w];
        }
        out[0] = LC * t0;                              // cls_loss
        out[1] = LC * t1;                              // conf_loss
        out[2] = LC * t2;                              // center+wh
        out[3] = LN * t3 + LC * (t0 + t1 + t2);        // total
    }
}

extern "C" void kernel_launch(void* const* d_in, const int* in_sizes, int n_in,
                              void* d_out, int out_size, void* d_ws, size_t ws_size,
                              hipStream_t stream) {
    const float* P = (const float*)d_in[0];
    const float* T = (const float*)d_in[1];
    float* out = (float*)d_out;
    float4* ws = (float4*)d_ws;          // GRID * 16 B = 50176 B of scratch

    yolo_partial<<<GRID, BLK, 0, stream>>>(P, T, ws);
    yolo_reduce<<<1, 1024, 0, stream>>>(ws, out);
}